// Round 3
// baseline (97053.119 us; speedup 1.0000x reference)
//
#include <hip/hip_runtime.h>
#include <math.h>

#define S_LEN 4096
#define HID   2048
#define NBLK  256
#define NTHR  512   // 8 waves/block, 1 block/CU

// R3: dataflow sync instead of a barrier.
//  - block b owns hidden units [8b,8b+8) and their 32 gate columns; cx stays in-block.
//  - lane l of wave w holds W rows k = 4l + 256j + r (j=0..7, r=0..3) for its 4 columns:
//    128 persistent regs. hx is read straight from global as float4 (no LDS staging).
//  - per step: threads 0..255 poll flags[tid] >= t+1 in parallel (no atomic RMW, no
//    single hot line), acquire fence (buffer_inv), coalesced hx float4 loads, 128
//    FMAs/lane, wave shuffle-reduce, lanes 0..7 do cell math, publish 8 hx floats with
//    agent-scope stores + one RELEASE flag store (vmcnt(0) covers the wave's data stores).
//  - double buffer by t parity is safe: flag[b] >= t implies b's step t-1 loads returned.

__global__ __launch_bounds__(NTHR, 2)
void qlstm_persistent(const float* __restrict__ inp,     // (S,1,4)
                      const float* __restrict__ conv_w,  // (4)
                      const float* __restrict__ conv_b,  // (1)
                      const float* __restrict__ Wg,      // (2049, 8192) row-major
                      const float* __restrict__ bg,      // (8192)
                      float* __restrict__ out,           // S*H + H + H
                      float* __restrict__ ws)            // scratch (first 1KB zeroed)
{
    const int b   = blockIdx.x;
    const int tid = threadIdx.x;
    const int l   = tid & 63;
    const int wv  = tid >> 6;

    unsigned* flags = (unsigned*)ws;               // [256] epoch flags, 1 KB
    float* buf0 = ws + 256;                        // [HID] hx buffer, parity 0
    float* buf1 = ws + 256 + HID + 64;             // [HID] hx buffer, parity 1

    __shared__ __align__(16) float conv_lds[S_LEN];
    __shared__ float gates_lds[32];
    __shared__ float colw0[32];
    __shared__ float colb[32];

    // ---------------- init phase ----------------
    {
        const float cw0 = conv_w[0], cw1 = conv_w[1], cw2 = conv_w[2], cw3 = conv_w[3];
        const float cb  = conv_b[0];
        for (int g = tid; g < S_LEN; g += NTHR) {
            float4 x = ((const float4*)inp)[g];
            float v = x.x*cw0 + x.y*cw1 + x.z*cw2 + x.w*cw3 + cb;
            conv_lds[g] = 1.0f / (1.0f + expf(-v));
        }
    }

    // this wave's 4 global column indices
    int jcol[4];
    #pragma unroll
    for (int c = 0; c < 4; ++c) {
        int cgi  = 4*wv + c;
        int gate = cgi >> 3;
        int mi   = cgi & 7;
        jcol[c]  = (gate << 11) + (b * 8 + mi);     // gate*2048 + m
    }
    if (l == 0) {
        #pragma unroll
        for (int c = 0; c < 4; ++c) {
            int cgi = 4*wv + c;
            colw0[cgi] = Wg[jcol[c]];               // row 0 = input (c_t) weight
            colb[cgi]  = bg[jcol[c]];
        }
    }

    // persistent W registers: wreg[c][4j+r] = W[1 + 4l + 256j + r][jcol[c]]
    float wreg[4][32];
    #pragma unroll
    for (int j = 0; j < 8; ++j)
        #pragma unroll
        for (int r = 0; r < 4; ++r) {
            const float* rowp = Wg + (size_t)(1 + 4*l + 256*j + r) * 8192;
            #pragma unroll
            for (int c = 0; c < 4; ++c)
                wreg[c][4*j + r] = rowp[jcol[c]];
        }

    float cx = 0.0f;                    // live only in lanes tid<8
    const int m_out = b * 8 + tid;      // hidden index for tid<8

    // publish initial hx = 0 (epoch 1): agent-scope data stores + release flag
    if (tid < 8)
        __hip_atomic_store(&buf0[m_out], 0.0f, __ATOMIC_RELAXED,
                           __HIP_MEMORY_SCOPE_AGENT);
    if (tid == 0)
        __hip_atomic_store(&flags[b], 1u, __ATOMIC_RELEASE,
                           __HIP_MEMORY_SCOPE_AGENT);

    // ---------------- recurrence ----------------
    for (int t = 0; t < S_LEN; ++t) {
        const unsigned want = (unsigned)(t + 1);

        // wait: 256 parallel read-only polls (16 lines), no RMW, no hot line
        if (tid < 256) {
            while (__hip_atomic_load(&flags[tid], __ATOMIC_RELAXED,
                                     __HIP_MEMORY_SCOPE_AGENT) < want) { }
        }
        __syncthreads();
        __builtin_amdgcn_fence(__ATOMIC_ACQUIRE, "agent");   // invalidate stale hx lines

        const float4* hb = (const float4*)((t & 1) ? buf1 : buf0);
        float*        bn = (t & 1) ? buf0 : buf1;

        float acc0 = 0.f, acc1 = 0.f, acc2 = 0.f, acc3 = 0.f;
        #pragma unroll
        for (int j = 0; j < 8; ++j) {
            float4 h = hb[l + 64*j];        // coalesced 1KB/wave-load, from L2/IC
            acc0 = fmaf(h.x, wreg[0][4*j+0], acc0);
            acc1 = fmaf(h.x, wreg[1][4*j+0], acc1);
            acc2 = fmaf(h.x, wreg[2][4*j+0], acc2);
            acc3 = fmaf(h.x, wreg[3][4*j+0], acc3);
            acc0 = fmaf(h.y, wreg[0][4*j+1], acc0);
            acc1 = fmaf(h.y, wreg[1][4*j+1], acc1);
            acc2 = fmaf(h.y, wreg[2][4*j+1], acc2);
            acc3 = fmaf(h.y, wreg[3][4*j+1], acc3);
            acc0 = fmaf(h.z, wreg[0][4*j+2], acc0);
            acc1 = fmaf(h.z, wreg[1][4*j+2], acc1);
            acc2 = fmaf(h.z, wreg[2][4*j+2], acc2);
            acc3 = fmaf(h.z, wreg[3][4*j+2], acc3);
            acc0 = fmaf(h.w, wreg[0][4*j+3], acc0);
            acc1 = fmaf(h.w, wreg[1][4*j+3], acc1);
            acc2 = fmaf(h.w, wreg[2][4*j+3], acc2);
            acc3 = fmaf(h.w, wreg[3][4*j+3], acc3);
        }
        // 64-lane reduction
        #pragma unroll
        for (int off = 32; off; off >>= 1) {
            acc0 += __shfl_down(acc0, off, 64);
            acc1 += __shfl_down(acc1, off, 64);
            acc2 += __shfl_down(acc2, off, 64);
            acc3 += __shfl_down(acc3, off, 64);
        }
        if (l == 0) {
            gates_lds[4*wv + 0] = acc0;
            gates_lds[4*wv + 1] = acc1;
            gates_lds[4*wv + 2] = acc2;
            gates_lds[4*wv + 3] = acc3;
        }
        __syncthreads();

        // cell math + publish: wave 0 only; release store's vmcnt(0) covers lanes 1..7
        if (tid < 8) {
            float ct = conv_lds[t];
            float fg = gates_lds[tid]      + ct*colw0[tid]      + colb[tid];
            float ig = gates_lds[8 + tid]  + ct*colw0[8 + tid]  + colb[8 + tid];
            float gg = gates_lds[16 + tid] + ct*colw0[16 + tid] + colb[16 + tid];
            float og = gates_lds[24 + tid] + ct*colw0[24 + tid] + colb[24 + tid];
            float f  = 1.0f / (1.0f + expf(-fg));
            float ii = 1.0f / (1.0f + expf(-ig));
            float gv = tanhf(gg);
            float o  = 1.0f / (1.0f + expf(-og));
            cx = f * cx + ii * gv;
            float hx = o * tanhf(cx);
            __hip_atomic_store(&bn[m_out], hx, __ATOMIC_RELAXED,
                               __HIP_MEMORY_SCOPE_AGENT);
        }
        if (tid == 0)
            __hip_atomic_store(&flags[b], (unsigned)(t + 2), __ATOMIC_RELEASE,
                               __HIP_MEMORY_SCOPE_AGENT);
        // out[] store off the critical path (after the flag publish)
        if (tid < 8) {
            float hx = bn[m_out];   // still in cache/registers; cheap re-read
            out[(size_t)t * HID + m_out] = hx;
            if (t == S_LEN - 1) {
                out[(size_t)S_LEN * HID + m_out]       = hx;   // final hx
                out[(size_t)S_LEN * HID + HID + m_out] = cx;   // final cx
            }
        }
    }
}

extern "C" void kernel_launch(void* const* d_in, const int* in_sizes, int n_in,
                              void* d_out, int out_size, void* d_ws, size_t ws_size,
                              hipStream_t stream) {
    const float* inp    = (const float*)d_in[0];
    const float* conv_w = (const float*)d_in[1];
    const float* conv_b = (const float*)d_in[2];
    const float* Wg     = (const float*)d_in[3];
    const float* bg     = (const float*)d_in[4];
    float* out = (float*)d_out;
    float* ws  = (float*)d_ws;

    // zero the epoch flags (ws is re-poisoned 0xAA before every timed launch;
    // poisoned flags would read as huge epochs and break the poll)
    hipMemsetAsync(ws, 0, 1024, stream);

    void* args[] = {(void*)&inp, (void*)&conv_w, (void*)&conv_b,
                    (void*)&Wg, (void*)&bg, (void*)&out, (void*)&ws};
    hipLaunchCooperativeKernel((void*)qlstm_persistent,
                               dim3(NBLK), dim3(NTHR), args, 0, stream);
}

// Round 4
// 11653.448 us; speedup vs baseline: 8.3283x; 8.3283x over previous
//
#include <hip/hip_runtime.h>
#include <math.h>

#define S_LEN 4096
#define HID   2048
#define NBLK  256
#define NTHR  512   // 8 waves/block, 1 block/CU

typedef unsigned long long u64;

// R4: tagged-data dataflow. Each hx element is published as one 8-byte atomic
// {f32 value | u32 epoch-tag}. No fences, no RMWs, no flags: the tag travels with
// the data, and relaxed agent-scope atomics bypass L1/L2 to the coherence point,
// so a consumer that sees tag==t+1 has the value by atomicity.
//  - block b owns hidden units [8b,8b+8); cx never leaves the block.
//  - all 8 waves poll: lane l of wave wv owns tagged entries e = wv*256 + 64j + l
//    (j=0..3), stages them into hx_lds on tag match. Exact-match polling means the
//    0xAA ws poison can never alias a tag (tags are 1..4097) -> no memset needed.
//  - parity double-buffer: overwriting buf[p] at end of step t+1 is safe because
//    seeing all tags t+2 implies every block's polls of buf[p] already returned.
//  - lane l of wave wv holds W rows 4l+256j+r for its 4 gate columns: 128
//    persistent regs, W never re-read after init.

__global__ __launch_bounds__(NTHR, 2)
void qlstm_persistent(const float* __restrict__ inp,     // (S,1,4)
                      const float* __restrict__ conv_w,  // (4)
                      const float* __restrict__ conv_b,  // (1)
                      const float* __restrict__ Wg,      // (2049, 8192) row-major
                      const float* __restrict__ bg,      // (8192)
                      float* __restrict__ out,           // S*H + H + H
                      float* __restrict__ ws)            // scratch (poison 0xAA ok)
{
    const int b   = blockIdx.x;
    const int tid = threadIdx.x;
    const int l   = tid & 63;
    const int wv  = tid >> 6;

    u64* tb0 = (u64*)ws;            // [HID] tagged hx, parity 0
    u64* tb1 = tb0 + HID + 16;      // [HID] tagged hx, parity 1 (line-padded)

    __shared__ __align__(16) float hx_lds[HID];
    __shared__ __align__(16) float conv_lds[S_LEN];
    __shared__ float gates_lds[32];
    __shared__ float colw0[32];
    __shared__ float colb[32];

    // ---------------- init phase ----------------
    {
        const float cw0 = conv_w[0], cw1 = conv_w[1], cw2 = conv_w[2], cw3 = conv_w[3];
        const float cb  = conv_b[0];
        for (int g = tid; g < S_LEN; g += NTHR) {
            float4 x = ((const float4*)inp)[g];
            float v = x.x*cw0 + x.y*cw1 + x.z*cw2 + x.w*cw3 + cb;
            conv_lds[g] = 1.0f / (1.0f + expf(-v));
        }
    }

    // this wave's 4 global column indices
    int jcol[4];
    #pragma unroll
    for (int c = 0; c < 4; ++c) {
        int cgi  = 4*wv + c;
        int gate = cgi >> 3;
        int mi   = cgi & 7;
        jcol[c]  = (gate << 11) + (b * 8 + mi);     // gate*2048 + m
    }
    if (l == 0) {
        #pragma unroll
        for (int c = 0; c < 4; ++c) {
            int cgi = 4*wv + c;
            colw0[cgi] = Wg[jcol[c]];               // row 0 = input (c_t) weight
            colb[cgi]  = bg[jcol[c]];
        }
    }

    // persistent W registers: wreg[c][4j+r] = W[1 + 4l + 256j + r][jcol[c]]
    float wreg[4][32];
    #pragma unroll
    for (int j = 0; j < 8; ++j)
        #pragma unroll
        for (int r = 0; r < 4; ++r) {
            const float* rowp = Wg + (size_t)(1 + 4*l + 256*j + r) * 8192;
            #pragma unroll
            for (int c = 0; c < 4; ++c)
                wreg[c][4*j + r] = rowp[jcol[c]];
        }

    float cx = 0.0f;                    // live only in lanes tid<8
    const int m_out = b * 8 + tid;      // hidden index for tid<8

    // publish hx_0 = 0 with tag 1 (single 8B atomic; tag travels with value)
    if (tid < 8)
        __hip_atomic_store(&tb0[m_out], (u64)1 << 32,
                           __ATOMIC_RELAXED, __HIP_MEMORY_SCOPE_AGENT);

    const int ebase = (wv << 8) + l;    // this thread's tagged-entry base

    // ---------------- recurrence ----------------
    for (int t = 0; t < S_LEN; ++t) {
        const unsigned want = (unsigned)(t + 1);
        u64* tb = (t & 1) ? tb1 : tb0;  // hx_t lives here, tag t+1
        u64* tn = (t & 1) ? tb0 : tb1;  // hx_{t+1} goes here, tag t+2

        // poll own 4 tagged entries (pipelined, retries touch only stragglers)
        u64 v0 = 0, v1 = 0, v2 = 0, v3 = 0;
        unsigned pend = 0xFu;
        do {
            if (pend & 1u) v0 = __hip_atomic_load(&tb[ebase      ], __ATOMIC_RELAXED, __HIP_MEMORY_SCOPE_AGENT);
            if (pend & 2u) v1 = __hip_atomic_load(&tb[ebase +  64], __ATOMIC_RELAXED, __HIP_MEMORY_SCOPE_AGENT);
            if (pend & 4u) v2 = __hip_atomic_load(&tb[ebase + 128], __ATOMIC_RELAXED, __HIP_MEMORY_SCOPE_AGENT);
            if (pend & 8u) v3 = __hip_atomic_load(&tb[ebase + 192], __ATOMIC_RELAXED, __HIP_MEMORY_SCOPE_AGENT);
            if ((unsigned)(v0 >> 32) == want) pend &= ~1u;
            if ((unsigned)(v1 >> 32) == want) pend &= ~2u;
            if ((unsigned)(v2 >> 32) == want) pend &= ~4u;
            if ((unsigned)(v3 >> 32) == want) pend &= ~8u;
        } while (pend);
        hx_lds[ebase      ] = __uint_as_float((unsigned)v0);
        hx_lds[ebase +  64] = __uint_as_float((unsigned)v1);
        hx_lds[ebase + 128] = __uint_as_float((unsigned)v2);
        hx_lds[ebase + 192] = __uint_as_float((unsigned)v3);
        __syncthreads();                       // A: hx_lds complete

        const float4* hl = (const float4*)hx_lds;
        float acc0 = 0.f, acc1 = 0.f, acc2 = 0.f, acc3 = 0.f;
        #pragma unroll
        for (int j = 0; j < 8; ++j) {
            float4 h = hl[l + 64*j];           // ds_read_b128, conflict-free
            acc0 = fmaf(h.x, wreg[0][4*j+0], acc0);
            acc1 = fmaf(h.x, wreg[1][4*j+0], acc1);
            acc2 = fmaf(h.x, wreg[2][4*j+0], acc2);
            acc3 = fmaf(h.x, wreg[3][4*j+0], acc3);
            acc0 = fmaf(h.y, wreg[0][4*j+1], acc0);
            acc1 = fmaf(h.y, wreg[1][4*j+1], acc1);
            acc2 = fmaf(h.y, wreg[2][4*j+1], acc2);
            acc3 = fmaf(h.y, wreg[3][4*j+1], acc3);
            acc0 = fmaf(h.z, wreg[0][4*j+2], acc0);
            acc1 = fmaf(h.z, wreg[1][4*j+2], acc1);
            acc2 = fmaf(h.z, wreg[2][4*j+2], acc2);
            acc3 = fmaf(h.z, wreg[3][4*j+2], acc3);
            acc0 = fmaf(h.w, wreg[0][4*j+3], acc0);
            acc1 = fmaf(h.w, wreg[1][4*j+3], acc1);
            acc2 = fmaf(h.w, wreg[2][4*j+3], acc2);
            acc3 = fmaf(h.w, wreg[3][4*j+3], acc3);
        }
        #pragma unroll
        for (int off = 32; off; off >>= 1) {
            acc0 += __shfl_down(acc0, off, 64);
            acc1 += __shfl_down(acc1, off, 64);
            acc2 += __shfl_down(acc2, off, 64);
            acc3 += __shfl_down(acc3, off, 64);
        }
        if (l == 0) {
            gates_lds[4*wv + 0] = acc0;
            gates_lds[4*wv + 1] = acc1;
            gates_lds[4*wv + 2] = acc2;
            gates_lds[4*wv + 3] = acc3;
        }
        __syncthreads();                       // B: gates complete

        if (tid < 8) {
            float ct = conv_lds[t];
            float fg = gates_lds[tid]      + ct*colw0[tid]      + colb[tid];
            float ig = gates_lds[8 + tid]  + ct*colw0[8 + tid]  + colb[8 + tid];
            float gg = gates_lds[16 + tid] + ct*colw0[16 + tid] + colb[16 + tid];
            float og = gates_lds[24 + tid] + ct*colw0[24 + tid] + colb[24 + tid];
            float f  = 1.0f / (1.0f + expf(-fg));
            float ii = 1.0f / (1.0f + expf(-ig));
            float gv = tanhf(gg);
            float o  = 1.0f / (1.0f + expf(-og));
            cx = f * cx + ii * gv;
            float hx = o * tanhf(cx);
            // publish: one 8B atomic carrying {value, tag t+2}
            __hip_atomic_store(&tn[m_out],
                               ((u64)(unsigned)(t + 2) << 32) | (u64)__float_as_uint(hx),
                               __ATOMIC_RELAXED, __HIP_MEMORY_SCOPE_AGENT);
            out[(size_t)t * HID + m_out] = hx;
            if (t == S_LEN - 1) {
                out[(size_t)S_LEN * HID + m_out]       = hx;   // final hx
                out[(size_t)S_LEN * HID + HID + m_out] = cx;   // final cx
            }
        }
    }
}

extern "C" void kernel_launch(void* const* d_in, const int* in_sizes, int n_in,
                              void* d_out, int out_size, void* d_ws, size_t ws_size,
                              hipStream_t stream) {
    const float* inp    = (const float*)d_in[0];
    const float* conv_w = (const float*)d_in[1];
    const float* conv_b = (const float*)d_in[2];
    const float* Wg     = (const float*)d_in[3];
    const float* bg     = (const float*)d_in[4];
    float* out = (float*)d_out;
    float* ws  = (float*)d_ws;

    // no memset needed: exact-match tags (1..4097) can never alias 0xAA poison

    void* args[] = {(void*)&inp, (void*)&conv_w, (void*)&conv_b,
                    (void*)&Wg, (void*)&bg, (void*)&out, (void*)&ws};
    hipLaunchCooperativeKernel((void*)qlstm_persistent,
                               dim3(NBLK), dim3(NTHR), args, 0, stream);
}